// Round 4
// baseline (277.094 us; speedup 1.0000x reference)
//
#include <hip/hip_runtime.h>
#include <math.h>

#define NROWS 65536
#define DIM   256
#define KCB   1024
#define TM    32
#define NBLK  (NROWS / TM)     // 2048
#define QOFF  (NROWS * DIM)
#define IDXOFF (QOFF + 1)

// ws float layout
#define WS_DMIN 0
#define WS_PLP  1
#define WS_AVGP 4                        // 8 replicas x 1024 floats
#define WS_C2   (WS_AVGP + 8 * 1024)
#define WS_CBF  (WS_C2 + 1024)           // fragment-ordered hi-bf16 codebook, 131072 ushort

#define DELTA 0.05f
#define XBP   264                        // ushort pitch of bf16 x tile (528 B/row)

typedef __attribute__((ext_vector_type(8))) __bf16 bf16x8;
typedef __attribute__((ext_vector_type(4))) float  f32x4;
typedef __attribute__((ext_vector_type(8))) unsigned short u16x8;
typedef __attribute__((ext_vector_type(4))) unsigned short u16x4;

// epilogue LDS float offsets (TM=32: 3264 floats = 13056 B)
#define EP_REDD 0       // [8][32]
#define EP_REDK 256
#define EP_RT1  512
#define EP_RT2  768
#define EP_GMIN 1024    // 32
#define EP_CNT  1056    // 32
#define EP_CAND 1088    // 32*16
#define EP_CEX  1600    // 32*16
#define EP_R1F  2112    // 32
#define EP_SP   2144    // 32
#define EP_KFIN 2176    // 32
#define EP_DFIN 2208    // 32
#define EP_AVGP 2240    // 1024
#define EP_SIZE 3264

__device__ __forceinline__ unsigned short f2bf(float f) {
    unsigned u = __float_as_uint(f);
    u += 0x7fffu + ((u >> 16) & 1u);
    return (unsigned short)(u >> 16);
}

// ---------------- prep: coalesced, 128 blocks ----------------
// gid in [0,32768): k = gid>>5 (codebook row), sub = gid&31 -> kc = sub>>2, qq = sub&3.
// Consecutive threads read consecutive 32B chunks of one row (wave = 2 KB contiguous).
__global__ __launch_bounds__(256) void prep_kernel(const float* __restrict__ cb,
                                                   float* __restrict__ ws) {
    int gid = blockIdx.x * 256 + threadIdx.x;   // 0..32767
    if (gid < 4) ws[gid] = 0.f;
    if (gid < 8192) ws[WS_AVGP + gid] = 0.f;    // 8x1024 replica region

    int k  = gid >> 5;
    int s  = gid & 31;
    int kc = s >> 2;
    int qq = s & 3;

    if (gid < 1024) {
        // c2 on the EXACT round-1 grid (sequential float4 chain), one thread per row
        const float4* row = (const float4*)(cb + (size_t)gid * DIM);
        float ssum = 0.f;
#pragma unroll 8
        for (int i = 0; i < DIM / 4; ++i) {
            float4 v = row[i];
            ssum += v.x * v.x + v.y * v.y + v.z * v.z + v.w * v.w;
        }
        ws[WS_C2 + gid] = ssum;
    }

    // fragment-ordered hi-bf16: chunk[((kc*1024 + k)*4 + qq)] = bf16(cb[k][kc*32+qq*8 .. +8])
    unsigned short* cbf = (unsigned short*)(ws + WS_CBF);
    const float* src = cb + (size_t)k * DIM + (kc << 5) + (qq << 3);
    float4 v0 = *(const float4*)src, v1 = *(const float4*)(src + 4);
    u16x8 o;
    o[0] = f2bf(v0.x); o[1] = f2bf(v0.y); o[2] = f2bf(v0.z); o[3] = f2bf(v0.w);
    o[4] = f2bf(v1.x); o[5] = f2bf(v1.y); o[6] = f2bf(v1.z); o[7] = f2bf(v1.w);
    *(u16x8*)(cbf + ((((size_t)(kc << 10) + k) << 2) + qq) * 8) = o;
}

// ---------------- main fused kernel ----------------
// TM=32 / 512 threads (8 waves, one col-group each). x tile converted ONCE to bf16 at
// staging and held in LDS (16.9 KB) -> zero f2bf in the MFMA loop. Total LDS ~30 KB and
// __launch_bounds__(512,4) caps regs at 128 (64 AGPR acc + <=64 VGPR) -> 2 blocks/CU:
// independent blocks overlap each other's barriers / serial phases / memory stalls.
__global__ __launch_bounds__(512, 4) void vq_main(const float* __restrict__ x,
                                                  const float* __restrict__ cb,
                                                  float* __restrict__ ws,
                                                  float* __restrict__ out) {
    __shared__ float epi[EP_SIZE];
    __shared__ unsigned short xs[32 * XBP];   // 16896 B, bf16 x tile

    const int tid  = threadIdx.x;
    const int w    = tid >> 6;       // 0..7 col group
    const int lane = tid & 63;
    const int m    = lane & 15;
    const int q    = lane >> 4;
    const int R0   = blockIdx.x * TM;

    const u16x8* cbf = (const u16x8*)(ws + WS_CBF);
    // chunk index = (kc*1024 + c)*4 + q, c = h*512 + w*64 + ct*16 + m
    const u16x8* bbase = cbf + (((w << 6) + m) << 2) + q;
    // steps in u16x8 units: kc: 4096, h: 2048, ct: 64

    u16x8 breg[2][4];
    bf16x8 ah[2];

    // ---- stage x rows (wave w -> rows 4w..4w+3): global fp32 -> bf16 LDS (convert once)
    float4 t0 = *((const float4*)(x + (size_t)(R0 + (w << 2) + 0) * DIM) + lane);
    float4 t1 = *((const float4*)(x + (size_t)(R0 + (w << 2) + 1) * DIM) + lane);
    float4 t2 = *((const float4*)(x + (size_t)(R0 + (w << 2) + 2) * DIM) + lane);
    float4 t3 = *((const float4*)(x + (size_t)(R0 + (w << 2) + 3) * DIM) + lane);

    // B prologue loads go out while x loads are in flight
    {
        const u16x8* p = bbase;  // sub 0: kc=0,h=0
        breg[0][0] = p[0]; breg[0][1] = p[64]; breg[0][2] = p[128]; breg[0][3] = p[192];
    }

    {
        u16x4 o;
        o[0] = f2bf(t0.x); o[1] = f2bf(t0.y); o[2] = f2bf(t0.z); o[3] = f2bf(t0.w);
        *(u16x4*)(xs + ((w << 2) + 0) * XBP + (lane << 2)) = o;
        o[0] = f2bf(t1.x); o[1] = f2bf(t1.y); o[2] = f2bf(t1.z); o[3] = f2bf(t1.w);
        *(u16x4*)(xs + ((w << 2) + 1) * XBP + (lane << 2)) = o;
        o[0] = f2bf(t2.x); o[1] = f2bf(t2.y); o[2] = f2bf(t2.z); o[3] = f2bf(t2.w);
        *(u16x4*)(xs + ((w << 2) + 2) * XBP + (lane << 2)) = o;
        o[0] = f2bf(t3.x); o[1] = f2bf(t3.y); o[2] = f2bf(t3.z); o[3] = f2bf(t3.w);
        *(u16x4*)(xs + ((w << 2) + 3) * XBP + (lane << 2)) = o;
    }

    f32x4 acc[2][8];
#pragma unroll
    for (int a = 0; a < 2; ++a)
#pragma unroll
        for (int b = 0; b < 8; ++b) acc[a][b] = (f32x4)0.f;

    __syncthreads();

    ah[0] = __builtin_bit_cast(bf16x8, *(const u16x8*)(xs + m * XBP + (q << 3)));
    ah[1] = __builtin_bit_cast(bf16x8, *(const u16x8*)(xs + (16 + m) * XBP + (q << 3)));

#pragma unroll
    for (int sub = 0; sub < 16; ++sub) {
        const int pb = sub & 1;
        if (sub < 15) {
            const int ns = sub + 1;
            const u16x8* p = bbase + ((ns >> 1) << 12) + ((ns & 1) << 11);
            breg[pb ^ 1][0] = p[0];   breg[pb ^ 1][1] = p[64];
            breg[pb ^ 1][2] = p[128]; breg[pb ^ 1][3] = p[192];
        }
#pragma unroll
        for (int ct = 0; ct < 4; ++ct) {
            bf16x8 bh = __builtin_bit_cast(bf16x8, breg[pb][ct]);
            int cg = ((sub & 1) << 2) + ct;
            acc[0][cg] = __builtin_amdgcn_mfma_f32_16x16x32_bf16(ah[0], bh, acc[0][cg], 0, 0, 0);
            acc[1][cg] = __builtin_amdgcn_mfma_f32_16x16x32_bf16(ah[1], bh, acc[1][cg], 0, 0, 0);
        }
        if ((sub & 1) == 1 && sub < 15) {
            const int nkc = (sub >> 1) + 1;
            ah[0] = __builtin_bit_cast(bf16x8, *(const u16x8*)(xs + m * XBP + (nkc << 5) + (q << 3)));
            ah[1] = __builtin_bit_cast(bf16x8, *(const u16x8*)(xs + (16 + m) * XBP + (nkc << 5) + (q << 3)));
        }
    }

    // ================= epilogue (rows = 32) =================
    // E0: zero accumulators; g = c2 - 2*acc (screen grid); per-wave per-row argmin
    if (tid < 32) ((int*)(epi + EP_CNT))[tid] = 0;
#pragma unroll
    for (int t = tid; t < 1024; t += 512) epi[EP_AVGP + t] = 0.f;

    float c2v[8];
#pragma unroll
    for (int cg = 0; cg < 8; ++cg) {
        int col = ((cg >> 2) << 9) + (w << 6) + ((cg & 3) << 4) + m;
        c2v[cg] = ws[WS_C2 + col];
    }
#pragma unroll
    for (int rt = 0; rt < 2; ++rt) {
#pragma unroll
        for (int reg = 0; reg < 4; ++reg) {
            int row = (rt << 4) + (q << 2) + reg;
            float md = 3.0e38f; int mk = 0;
#pragma unroll
            for (int cg = 0; cg < 8; ++cg) {
                float g = c2v[cg] - 2.0f * acc[rt][cg][reg];
                acc[rt][cg][reg] = g;
                int col = ((cg >> 2) << 9) + (w << 6) + ((cg & 3) << 4) + m;
                if (g < md) { md = g; mk = col; }
            }
#pragma unroll
            for (int off = 1; off <= 8; off <<= 1) {
                float od = __shfl_xor(md, off, 64);
                int   ok = __shfl_xor(mk, off, 64);
                if (od < md || (od == md && ok < mk)) { md = od; mk = ok; }
            }
            if (m == 0) {
                epi[EP_REDD + (w << 5) + row] = md;
                ((int*)(epi + EP_REDK))[(w << 5) + row] = mk;
            }
        }
    }
    __syncthreads();

    // E1: cross-wave min per row
    if (tid < 32) {
        float gm = 3.0e38f;
#pragma unroll
        for (int wv = 0; wv < 8; ++wv) {
            float d = epi[EP_REDD + (wv << 5) + tid];
            if (d < gm) gm = d;
        }
        epi[EP_GMIN + tid] = gm;
    }
    __syncthreads();

    // E2: exp pass + candidate collection + per-wave T1/T2
    {
        int* cnt  = (int*)(epi + EP_CNT);
        int* cand = (int*)(epi + EP_CAND);
#pragma unroll
        for (int rt = 0; rt < 2; ++rt) {
#pragma unroll
            for (int reg = 0; reg < 4; ++reg) {
                int row = (rt << 4) + (q << 2) + reg;
                float gm = epi[EP_GMIN + row];
                float t1 = 0.f, t2 = 0.f;
#pragma unroll
                for (int cg = 0; cg < 8; ++cg) {
                    float g = acc[rt][cg][reg];
                    if (g < gm + DELTA) {
                        int col = ((cg >> 2) << 9) + (w << 6) + ((cg & 3) << 4) + m;
                        int pos = atomicAdd(&cnt[row], 1);
                        if (pos < 16) cand[(row << 4) + pos] = col;
                    }
                    float z = -100.0f * (g - gm);
                    float e = __expf(z);
                    acc[rt][cg][reg] = e;
                    t1 += e;
                    t2 += e * z;
                }
#pragma unroll
                for (int off = 1; off <= 8; off <<= 1) {
                    t1 += __shfl_xor(t1, off, 64);
                    t2 += __shfl_xor(t2, off, 64);
                }
                if (m == 0) {
                    epi[EP_RT1 + (w << 5) + row] = t1;
                    epi[EP_RT2 + (w << 5) + row] = t2;
                }
            }
        }
    }
    __syncthreads();

    // E3: finalize per-row softmax stats
    if (tid < 32) {
        float T1 = 0.f, T2 = 0.f;
#pragma unroll
        for (int wv = 0; wv < 8; ++wv) {
            T1 += epi[EP_RT1 + (wv << 5) + tid];
            T2 += epi[EP_RT2 + (wv << 5) + tid];
        }
        float r1 = 1.0f / T1;
        epi[EP_R1F + tid] = r1;
        epi[EP_SP + tid]  = T2 * r1 - logf(T1);
    }
    __syncthreads();

    // E4a: avg_probs column sums (each wave owns its 64 cols per half -> no race)
    {
        float r1v[2][4];
#pragma unroll
        for (int rt = 0; rt < 2; ++rt)
#pragma unroll
            for (int reg = 0; reg < 4; ++reg)
                r1v[rt][reg] = epi[EP_R1F + (rt << 4) + (q << 2) + reg];
#pragma unroll
        for (int cg = 0; cg < 8; ++cg) {
            float s = 0.f;
#pragma unroll
            for (int rt = 0; rt < 2; ++rt)
#pragma unroll
                for (int reg = 0; reg < 4; ++reg)
                    s += acc[rt][cg][reg] * r1v[rt][reg];
            s += __shfl_xor(s, 16, 64);
            s += __shfl_xor(s, 32, 64);
            if (lane < 16) {
                int col = ((cg >> 2) << 9) + (w << 6) + ((cg & 3) << 4) + m;
                epi[EP_AVGP + col] += s;
            }
        }
    }
    // E4b: candidate refinement on the EXACT round-1/np grid (global fp32 x, unrolled):
    //      d = (x2 - 2*ab) + c2; ab sequential fmaf chain; x2 round-1 expression.
    {
        int* cnt  = (int*)(epi + EP_CNT);
        int* cand = (int*)(epi + EP_CAND);
        int r = tid >> 4;          // 32 rows x 16 threads = 512
        int i = tid & 15;
        int n = cnt[r]; if (n > 16) n = 16;
        if (i < n) {
            int k = cand[(r << 4) + i];
            const float4* ax = (const float4*)(x  + (((size_t)(R0 + r)) << 8));
            const float4* bx = (const float4*)(cb + (((size_t)k) << 8));
            float ab = 0.f, x2 = 0.f;
#pragma unroll 8
            for (int d4 = 0; d4 < 64; ++d4) {
                float4 a = ax[d4], b = bx[d4];
                ab = fmaf(a.x, b.x, ab);
                ab = fmaf(a.y, b.y, ab);
                ab = fmaf(a.z, b.z, ab);
                ab = fmaf(a.w, b.w, ab);
                x2 += a.x * a.x + a.y * a.y + a.z * a.z + a.w * a.w;
            }
            float t = 2.0f * ab;
            epi[EP_CEX + (r << 4) + i] = (x2 - t) + ws[WS_C2 + k];
        }
    }
    __syncthreads();

    // E5: final per-row selection (min d, lowest-index tie-break) + index output
    if (tid < 32) {
        int* cnt  = (int*)(epi + EP_CNT);
        int* cand = (int*)(epi + EP_CAND);
        int n = cnt[tid]; if (n > 16) n = 16;
        float bd = epi[EP_CEX + (tid << 4)];
        int   bk = cand[(tid << 4)];
        for (int i = 1; i < n; ++i) {
            float d = epi[EP_CEX + (tid << 4) + i];
            int   k = cand[(tid << 4) + i];
            if (d < bd || (d == bd && k < bk)) { bd = d; bk = k; }
        }
        ((int*)(epi + EP_KFIN))[tid] = bk;
        epi[EP_DFIN + tid] = bd;
        out[IDXOFF + R0 + tid] = (float)bk;
    }
    __syncthreads();

    // E6: quantized gather (wave w -> rows w*4..w*4+3, nt stores), global accumulators
#pragma unroll
    for (int rr = 0; rr < 4; ++rr) {
        int r = (w << 2) + rr;
        int k = ((int*)(epi + EP_KFIN))[r];
        f32x4 v = *((const f32x4*)(cb + (((size_t)k) << 8)) + lane);
        __builtin_nontemporal_store(v, (f32x4*)(out + (((size_t)(R0 + r)) << 8)) + lane);
    }
    // replicated avg_probs accumulator: contention /8
    for (int t = tid; t < 1024; t += 512)
        atomicAdd(ws + WS_AVGP + ((blockIdx.x & 7) << 10) + t, epi[EP_AVGP + t]);
    if (tid < 32) {
        float sp = epi[EP_SP + tid];
        float dd = epi[EP_DFIN + tid];
#pragma unroll
        for (int off = 1; off <= 16; off <<= 1) {
            sp += __shfl_xor(sp, off, 64);
            dd += __shfl_xor(dd, off, 64);
        }
        if (tid == 0) {
            atomicAdd(ws + WS_PLP, sp);
            atomicAdd(ws + WS_DMIN, dd);
        }
    }
}

// ---------------- finalize ----------------
__global__ __launch_bounds__(256) void vq_finalize(const float* __restrict__ ws,
                                                   float* __restrict__ out) {
    __shared__ float red[4];
    int tid = threadIdx.x;
    float part = 0.f;
    for (int k = tid; k < 1024; k += 256) {
        float s = 0.f;
#pragma unroll
        for (int r = 0; r < 8; ++r) s += ws[WS_AVGP + (r << 10) + k];
        float ap = s * (1.0f / 65536.0f);
        part += ap * logf(ap + 1e-5f);
    }
#pragma unroll
    for (int off = 32; off; off >>= 1) part += __shfl_xor(part, off, 64);
    if ((tid & 63) == 0) red[tid >> 6] = part;
    __syncthreads();
    if (tid == 0) {
        float sum_aplog      = red[0] + red[1] + red[2] + red[3];
        float avg_entropy    = -sum_aplog;
        float sample_entropy = -ws[WS_PLP] * (1.0f / 65536.0f);
        float entropy_loss   = (sample_entropy - avg_entropy) * 0.1f;
        float eq = 1.25f * ws[WS_DMIN] * (1.0f / ((float)NROWS * (float)DIM));
        out[QOFF] = eq + entropy_loss;
    }
}

extern "C" void kernel_launch(void* const* d_in, const int* in_sizes, int n_in,
                              void* d_out, int out_size, void* d_ws, size_t ws_size,
                              hipStream_t stream) {
    const float* x  = (const float*)d_in[0];
    const float* cb = (const float*)d_in[1];
    float* out = (float*)d_out;
    float* ws  = (float*)d_ws;

    prep_kernel<<<128, 256, 0, stream>>>(cb, ws);
    vq_main<<<NBLK, 512, 0, stream>>>(x, cb, ws, out);
    vq_finalize<<<1, 256, 0, stream>>>(ws, out);
}

// Round 5
// 264.737 us; speedup vs baseline: 1.0467x; 1.0467x over previous
//
#include <hip/hip_runtime.h>
#include <math.h>

#define NROWS 65536
#define DIM   256
#define KCB   1024
#define TM    64
#define NBLK  (NROWS / TM)     // 1024
#define QOFF  (NROWS * DIM)
#define IDXOFF (QOFF + 1)

// ws float layout
#define WS_DMIN 0
#define WS_PLP  1
#define WS_AVGP 4                        // 8 replicas x 1024 floats (atomic contention /8)
#define WS_C2   (WS_AVGP + 8 * 1024)
#define WS_CBF  (WS_C2 + 1024)           // fragment-ordered hi-bf16 codebook, 131072 ushort

#define DELTA 0.05f
#define XPITCH 260                       // fp32 LDS x pitch (floats)
#define XBU    264                       // bf16 LDS x pitch (ushorts, 528 B rows)

typedef __attribute__((ext_vector_type(8))) __bf16 bf16x8;
typedef __attribute__((ext_vector_type(4))) float  f32x4;
typedef __attribute__((ext_vector_type(8))) unsigned short u16x8;
typedef __attribute__((ext_vector_type(4))) unsigned short u16x4;

// epilogue LDS float offsets (static shared, 5504 floats = 22016 B)
#define EP_REDD 0       // [8][64]
#define EP_REDK 512     // [8][64] int
#define EP_RT1  1024    // [8][64]
#define EP_RT2  1536    // [8][64]
#define EP_GMIN 2048    // 64
#define EP_CNT  2112    // 64 int
#define EP_CAND 2176    // 64*16 int
#define EP_CEX  3200    // 64*16
#define EP_R1F  4224    // 64
#define EP_SP   4288    // 64
#define EP_KFIN 4352    // 64 int
#define EP_DFIN 4416    // 64
#define EP_AVGP 4480    // 1024
#define EP_SIZE 5504

__device__ __forceinline__ unsigned short f2bf(float f) {
    unsigned u = __float_as_uint(f);
    u += 0x7fffu + ((u >> 16) & 1u);
    return (unsigned short)(u >> 16);
}

// ---------------- prep: coalesced, 128 blocks ----------------
__global__ __launch_bounds__(256) void prep_kernel(const float* __restrict__ cb,
                                                   float* __restrict__ ws) {
    int gid = blockIdx.x * 256 + threadIdx.x;   // 0..32767
    if (gid < 4) ws[gid] = 0.f;
    if (gid < 8192) ws[WS_AVGP + gid] = 0.f;    // 8x1024 replica region

    int k  = gid >> 5;
    int s  = gid & 31;
    int kc = s >> 2;
    int qq = s & 3;

    if (gid < 1024) {
        // c2 on the EXACT round-1 grid (sequential float4 chain), one thread per row
        const float4* row = (const float4*)(cb + (size_t)gid * DIM);
        float ssum = 0.f;
#pragma unroll 8
        for (int i = 0; i < DIM / 4; ++i) {
            float4 v = row[i];
            ssum += v.x * v.x + v.y * v.y + v.z * v.z + v.w * v.w;
        }
        ws[WS_C2 + gid] = ssum;
    }

    // fragment-ordered hi-bf16: chunk[((kc*1024 + k)*4 + qq)] = bf16(cb[k][kc*32+qq*8 .. +8])
    unsigned short* cbf = (unsigned short*)(ws + WS_CBF);
    const float* src = cb + (size_t)k * DIM + (kc << 5) + (qq << 3);
    float4 v0 = *(const float4*)src, v1 = *(const float4*)(src + 4);
    u16x8 o;
    o[0] = f2bf(v0.x); o[1] = f2bf(v0.y); o[2] = f2bf(v0.z); o[3] = f2bf(v0.w);
    o[4] = f2bf(v1.x); o[5] = f2bf(v1.y); o[6] = f2bf(v1.z); o[7] = f2bf(v1.w);
    *(u16x8*)(cbf + ((((size_t)(kc << 10) + k) << 2) + qq) * 8) = o;
}

// ---------------- main fused kernel ----------------
// TM=64 / 1024 threads (16 waves = 2 row-halves x 8 col-groups): halved codebook traffic.
// x staged TWICE in LDS: fp32 (for E4b exact refinement) + bf16 (converted once at staging;
// main loop reads bf16x8 directly -> zero f2bf in the MFMA loop). Bit-identical to R3.
__global__ __launch_bounds__(1024, 4) void vq_main(const float* __restrict__ x,
                                                   const float* __restrict__ cb,
                                                   float* __restrict__ ws,
                                                   float* __restrict__ out) {
    __shared__ float epi[EP_SIZE];
    __shared__ float xs[64 * XPITCH];         // 66560 B fp32 x tile
    __shared__ unsigned short xbf[64 * XBU];  // 33792 B bf16 x tile

    const int tid  = threadIdx.x;
    const int w    = tid >> 6;       // 0..15
    const int lane = tid & 63;
    const int m    = lane & 15;
    const int q    = lane >> 4;
    const int wc   = w & 7;          // column group
    const int rh   = w >> 3;         // row half
    const int R0   = blockIdx.x * TM;

    const u16x8* cbf = (const u16x8*)(ws + WS_CBF);
    // chunk index = (kc*1024 + c)*4 + q, c = h*512 + wc*64 + ct*16 + m
    const u16x8* bbase = cbf + (((wc << 6) + m) << 2) + q;
    // steps in u16x8 units: kc: 4096, h: 2048, ct: 64

    u16x8 breg[2][4];
    bf16x8 ah[2];

    // ---- stage x rows (wave w -> rows 4w..4w+3); longest-latency loads first
    float4 t0 = *((const float4*)(x + (size_t)(R0 + (w << 2) + 0) * DIM) + lane);
    float4 t1 = *((const float4*)(x + (size_t)(R0 + (w << 2) + 1) * DIM) + lane);
    float4 t2 = *((const float4*)(x + (size_t)(R0 + (w << 2) + 2) * DIM) + lane);
    float4 t3 = *((const float4*)(x + (size_t)(R0 + (w << 2) + 3) * DIM) + lane);

    // B prologue loads go out while x loads are in flight
    {
        const u16x8* p = bbase;  // sub 0: kc=0,h=0
        breg[0][0] = p[0]; breg[0][1] = p[64]; breg[0][2] = p[128]; breg[0][3] = p[192];
    }

    // fp32 copy (E4b) + bf16 copy (MFMA loop) — f2bf on the same register values
    *((float4*)(xs + ((w << 2) + 0) * XPITCH) + lane) = t0;
    *((float4*)(xs + ((w << 2) + 1) * XPITCH) + lane) = t1;
    *((float4*)(xs + ((w << 2) + 2) * XPITCH) + lane) = t2;
    *((float4*)(xs + ((w << 2) + 3) * XPITCH) + lane) = t3;
    {
        u16x4 o;
        o[0] = f2bf(t0.x); o[1] = f2bf(t0.y); o[2] = f2bf(t0.z); o[3] = f2bf(t0.w);
        *(u16x4*)(xbf + ((w << 2) + 0) * XBU + (lane << 2)) = o;
        o[0] = f2bf(t1.x); o[1] = f2bf(t1.y); o[2] = f2bf(t1.z); o[3] = f2bf(t1.w);
        *(u16x4*)(xbf + ((w << 2) + 1) * XBU + (lane << 2)) = o;
        o[0] = f2bf(t2.x); o[1] = f2bf(t2.y); o[2] = f2bf(t2.z); o[3] = f2bf(t2.w);
        *(u16x4*)(xbf + ((w << 2) + 2) * XBU + (lane << 2)) = o;
        o[0] = f2bf(t3.x); o[1] = f2bf(t3.y); o[2] = f2bf(t3.z); o[3] = f2bf(t3.w);
        *(u16x4*)(xbf + ((w << 2) + 3) * XBU + (lane << 2)) = o;
    }

    f32x4 acc[2][8];
#pragma unroll
    for (int a = 0; a < 2; ++a)
#pragma unroll
        for (int b = 0; b < 8; ++b) acc[a][b] = (f32x4)0.f;

    __syncthreads();

    const int rbase = rh << 5;       // wave's 32-row base inside the LDS tile
    ah[0] = __builtin_bit_cast(bf16x8, *(const u16x8*)(xbf + (rbase + m) * XBU + (q << 3)));
    ah[1] = __builtin_bit_cast(bf16x8, *(const u16x8*)(xbf + (rbase + 16 + m) * XBU + (q << 3)));

#pragma unroll
    for (int sub = 0; sub < 16; ++sub) {
        const int pb = sub & 1;
        if (sub < 15) {
            const int ns = sub + 1;
            const u16x8* p = bbase + ((ns >> 1) << 12) + ((ns & 1) << 11);
            breg[pb ^ 1][0] = p[0];   breg[pb ^ 1][1] = p[64];
            breg[pb ^ 1][2] = p[128]; breg[pb ^ 1][3] = p[192];
        }
#pragma unroll
        for (int ct = 0; ct < 4; ++ct) {
            bf16x8 bh = __builtin_bit_cast(bf16x8, breg[pb][ct]);
            int cg = ((sub & 1) << 2) + ct;
            acc[0][cg] = __builtin_amdgcn_mfma_f32_16x16x32_bf16(ah[0], bh, acc[0][cg], 0, 0, 0);
            acc[1][cg] = __builtin_amdgcn_mfma_f32_16x16x32_bf16(ah[1], bh, acc[1][cg], 0, 0, 0);
        }
        if ((sub & 1) == 1 && sub < 15) {
            const int nkc = (sub >> 1) + 1;
            ah[0] = __builtin_bit_cast(bf16x8,
                *(const u16x8*)(xbf + (rbase + m) * XBU + (nkc << 5) + (q << 3)));
            ah[1] = __builtin_bit_cast(bf16x8,
                *(const u16x8*)(xbf + (rbase + 16 + m) * XBU + (nkc << 5) + (q << 3)));
        }
    }

    // ================= epilogue (rows = 64) =================
    // E0: zero accumulators; g = c2 - 2*acc (screen grid); per-wave per-row argmin
    if (tid < 64) ((int*)(epi + EP_CNT))[tid] = 0;
    epi[EP_AVGP + tid] = 0.f;            // 1024 threads, one each

    float c2v[8];
#pragma unroll
    for (int cg = 0; cg < 8; ++cg) {
        int col = ((cg >> 2) << 9) + (wc << 6) + ((cg & 3) << 4) + m;
        c2v[cg] = ws[WS_C2 + col];
    }
#pragma unroll
    for (int rt = 0; rt < 2; ++rt) {
#pragma unroll
        for (int reg = 0; reg < 4; ++reg) {
            int row = rbase + (rt << 4) + (q << 2) + reg;
            float md = 3.0e38f; int mk = 0;
#pragma unroll
            for (int cg = 0; cg < 8; ++cg) {
                float g = c2v[cg] - 2.0f * acc[rt][cg][reg];
                acc[rt][cg][reg] = g;
                int col = ((cg >> 2) << 9) + (wc << 6) + ((cg & 3) << 4) + m;
                if (g < md) { md = g; mk = col; }
            }
#pragma unroll
            for (int off = 1; off <= 8; off <<= 1) {
                float od = __shfl_xor(md, off, 64);
                int   ok = __shfl_xor(mk, off, 64);
                if (od < md || (od == md && ok < mk)) { md = od; mk = ok; }
            }
            if (m == 0) {
                epi[EP_REDD + (wc << 6) + row] = md;
                ((int*)(epi + EP_REDK))[(wc << 6) + row] = mk;
            }
        }
    }
    __syncthreads();

    // E1: cross-group min per row
    if (tid < 64) {
        float gm = 3.0e38f;
#pragma unroll
        for (int g = 0; g < 8; ++g) {
            float d = epi[EP_REDD + (g << 6) + tid];
            if (d < gm) gm = d;
        }
        epi[EP_GMIN + tid] = gm;
    }
    __syncthreads();

    // E2: exp pass + candidate collection + per-wave T1/T2
    {
        int* cnt  = (int*)(epi + EP_CNT);
        int* cand = (int*)(epi + EP_CAND);
#pragma unroll
        for (int rt = 0; rt < 2; ++rt) {
#pragma unroll
            for (int reg = 0; reg < 4; ++reg) {
                int row = rbase + (rt << 4) + (q << 2) + reg;
                float gm = epi[EP_GMIN + row];
                float t1 = 0.f, t2 = 0.f;
#pragma unroll
                for (int cg = 0; cg < 8; ++cg) {
                    float g = acc[rt][cg][reg];
                    if (g < gm + DELTA) {
                        int col = ((cg >> 2) << 9) + (wc << 6) + ((cg & 3) << 4) + m;
                        int pos = atomicAdd(&cnt[row], 1);
                        if (pos < 16) cand[(row << 4) + pos] = col;
                    }
                    float z = -100.0f * (g - gm);
                    float e = __expf(z);
                    acc[rt][cg][reg] = e;
                    t1 += e;
                    t2 += e * z;
                }
#pragma unroll
                for (int off = 1; off <= 8; off <<= 1) {
                    t1 += __shfl_xor(t1, off, 64);
                    t2 += __shfl_xor(t2, off, 64);
                }
                if (m == 0) {
                    epi[EP_RT1 + (wc << 6) + row] = t1;
                    epi[EP_RT2 + (wc << 6) + row] = t2;
                }
            }
        }
    }
    __syncthreads();

    // E3: finalize per-row softmax stats
    if (tid < 64) {
        float T1 = 0.f, T2 = 0.f;
#pragma unroll
        for (int g = 0; g < 8; ++g) {
            T1 += epi[EP_RT1 + (g << 6) + tid];
            T2 += epi[EP_RT2 + (g << 6) + tid];
        }
        float r1 = 1.0f / T1;
        epi[EP_R1F + tid] = r1;
        epi[EP_SP + tid]  = T2 * r1 - logf(T1);
    }
    __syncthreads();

    // E4a: avg_probs column sums (row-halves combined with a staggered += across barriers)
    float sv[8];
    {
        float r1v[2][4];
#pragma unroll
        for (int rt = 0; rt < 2; ++rt)
#pragma unroll
            for (int reg = 0; reg < 4; ++reg)
                r1v[rt][reg] = epi[EP_R1F + rbase + (rt << 4) + (q << 2) + reg];
#pragma unroll
        for (int cg = 0; cg < 8; ++cg) {
            float s = 0.f;
#pragma unroll
            for (int rt = 0; rt < 2; ++rt)
#pragma unroll
                for (int reg = 0; reg < 4; ++reg)
                    s += acc[rt][cg][reg] * r1v[rt][reg];
            s += __shfl_xor(s, 16, 64);
            s += __shfl_xor(s, 32, 64);
            sv[cg] = s;
        }
        if (rh == 0 && lane < 16) {
#pragma unroll
            for (int cg = 0; cg < 8; ++cg) {
                int col = ((cg >> 2) << 9) + (wc << 6) + ((cg & 3) << 4) + m;
                epi[EP_AVGP + col] += sv[cg];
            }
        }
    }
    // E4b: candidate refinement on the EXACT round-1/np grid:
    //      d = (x2 - 2*ab) + c2; ab sequential fmaf chain; ax from fp32 LDS; unrolled.
    {
        int* cnt  = (int*)(epi + EP_CNT);
        int* cand = (int*)(epi + EP_CAND);
        int r = tid >> 4;          // 64 rows x 16 threads = 1024
        int i = tid & 15;
        int n = cnt[r]; if (n > 16) n = 16;
        if (i < n) {
            int k = cand[(r << 4) + i];
            const float4* ax = (const float4*)(xs + r * XPITCH);
            const float4* bx = (const float4*)(cb + (((size_t)k) << 8));
            float ab = 0.f, x2 = 0.f;
#pragma unroll 8
            for (int d4 = 0; d4 < 64; ++d4) {
                float4 a = ax[d4], b = bx[d4];
                ab = fmaf(a.x, b.x, ab);
                ab = fmaf(a.y, b.y, ab);
                ab = fmaf(a.z, b.z, ab);
                ab = fmaf(a.w, b.w, ab);
                x2 += a.x * a.x + a.y * a.y + a.z * a.z + a.w * a.w;
            }
            float t = 2.0f * ab;
            epi[EP_CEX + (r << 4) + i] = (x2 - t) + ws[WS_C2 + k];
        }
    }
    __syncthreads();

    // second half of E4a (race-free via the barrier above)
    if (rh == 1 && lane < 16) {
#pragma unroll
        for (int cg = 0; cg < 8; ++cg) {
            int col = ((cg >> 2) << 9) + (wc << 6) + ((cg & 3) << 4) + m;
            epi[EP_AVGP + col] += sv[cg];
        }
    }

    // E5: final per-row selection (min d, lowest-index tie-break) + index output
    if (tid < 64) {
        int* cnt  = (int*)(epi + EP_CNT);
        int* cand = (int*)(epi + EP_CAND);
        int n = cnt[tid]; if (n > 16) n = 16;
        float bd = epi[EP_CEX + (tid << 4)];
        int   bk = cand[(tid << 4)];
        for (int i = 1; i < n; ++i) {
            float d = epi[EP_CEX + (tid << 4) + i];
            int   k = cand[(tid << 4) + i];
            if (d < bd || (d == bd && k < bk)) { bd = d; bk = k; }
        }
        ((int*)(epi + EP_KFIN))[tid] = bk;
        epi[EP_DFIN + tid] = bd;
        out[IDXOFF + R0 + tid] = (float)bk;
    }
    __syncthreads();

    // E6: quantized gather (wave w -> rows w*4..w*4+3, nt stores), global accumulators
#pragma unroll
    for (int rr = 0; rr < 4; ++rr) {
        int r = (w << 2) + rr;
        int k = ((int*)(epi + EP_KFIN))[r];
        f32x4 v = *((const f32x4*)(cb + (((size_t)k) << 8)) + lane);
        __builtin_nontemporal_store(v, (f32x4*)(out + (((size_t)(R0 + r)) << 8)) + lane);
    }
    // replicated avg_probs accumulator: contention /8
    atomicAdd(ws + WS_AVGP + ((blockIdx.x & 7) << 10) + tid, epi[EP_AVGP + tid]);
    if (tid < 64) {
        float sp = epi[EP_SP + tid];
        float dd = epi[EP_DFIN + tid];
#pragma unroll
        for (int off = 1; off <= 32; off <<= 1) {
            sp += __shfl_xor(sp, off, 64);
            dd += __shfl_xor(dd, off, 64);
        }
        if (tid == 0) {
            atomicAdd(ws + WS_PLP, sp);
            atomicAdd(ws + WS_DMIN, dd);
        }
    }
}

// ---------------- finalize ----------------
__global__ __launch_bounds__(256) void vq_finalize(const float* __restrict__ ws,
                                                   float* __restrict__ out) {
    __shared__ float red[4];
    int tid = threadIdx.x;
    float part = 0.f;
    for (int k = tid; k < 1024; k += 256) {
        float s = 0.f;
#pragma unroll
        for (int r = 0; r < 8; ++r) s += ws[WS_AVGP + (r << 10) + k];
        float ap = s * (1.0f / 65536.0f);
        part += ap * logf(ap + 1e-5f);
    }
#pragma unroll
    for (int off = 32; off; off >>= 1) part += __shfl_xor(part, off, 64);
    if ((tid & 63) == 0) red[tid >> 6] = part;
    __syncthreads();
    if (tid == 0) {
        float sum_aplog      = red[0] + red[1] + red[2] + red[3];
        float avg_entropy    = -sum_aplog;
        float sample_entropy = -ws[WS_PLP] * (1.0f / 65536.0f);
        float entropy_loss   = (sample_entropy - avg_entropy) * 0.1f;
        float eq = 1.25f * ws[WS_DMIN] * (1.0f / ((float)NROWS * (float)DIM));
        out[QOFF] = eq + entropy_loss;
    }
}

extern "C" void kernel_launch(void* const* d_in, const int* in_sizes, int n_in,
                              void* d_out, int out_size, void* d_ws, size_t ws_size,
                              hipStream_t stream) {
    const float* x  = (const float*)d_in[0];
    const float* cb = (const float*)d_in[1];
    float* out = (float*)d_out;
    float* ws  = (float*)d_ws;

    prep_kernel<<<128, 256, 0, stream>>>(cb, ws);
    vq_main<<<NBLK, 1024, 0, stream>>>(x, cb, ws, out);
    vq_finalize<<<1, 256, 0, stream>>>(ws, out);
}

// Round 6
// 259.845 us; speedup vs baseline: 1.0664x; 1.0188x over previous
//
#include <hip/hip_runtime.h>
#include <math.h>

#define NROWS 65536
#define DIM   256
#define KCB   1024
#define TM    64
#define NBLK  (NROWS / TM)     // 1024
#define QOFF  (NROWS * DIM)
#define IDXOFF (QOFF + 1)

// ws float layout
#define WS_DMIN 0
#define WS_PLP  1
#define WS_AVGP 4                        // 8 replicas x 1024 floats (atomic contention /8)
#define WS_C2   (WS_AVGP + 8 * 1024)
#define WS_CBF  (WS_C2 + 1024)           // fragment-ordered hi-bf16 codebook, 131072 ushort

#define DELTA 0.05f
#define XPITCH 260                       // fp32 LDS x pitch (floats)
#define XBU    264                       // bf16 LDS x pitch (ushorts, 528 B rows)

typedef __attribute__((ext_vector_type(8))) __bf16 bf16x8;
typedef __attribute__((ext_vector_type(4))) float  f32x4;
typedef __attribute__((ext_vector_type(8))) unsigned short u16x8;
typedef __attribute__((ext_vector_type(4))) unsigned short u16x4;

// epilogue LDS float offsets (static shared, 5504 floats = 22016 B)
#define EP_REDD 0       // [8][64]
#define EP_REDK 512     // [8][64] int
#define EP_RT1  1024    // [8][64]
#define EP_RT2  1536    // [8][64]
#define EP_GMIN 2048    // 64
#define EP_CNT  2112    // 64 int
#define EP_CAND 2176    // 64*16 int
#define EP_CEX  3200    // 64*16
#define EP_R1F  4224    // 64
#define EP_SP   4288    // 64
#define EP_KFIN 4352    // 64 int
#define EP_DFIN 4416    // 64
#define EP_AVGP 4480    // 1024
#define EP_SIZE 5504

__device__ __forceinline__ unsigned short f2bf(float f) {
    unsigned u = __float_as_uint(f);
    u += 0x7fffu + ((u >> 16) & 1u);
    return (unsigned short)(u >> 16);
}

// ---- DPP row_ror all-reduce helpers (16-lane rows, pure VALU, no DS pipe) ----
// ctrl: row_ror:N = 0x120|N. Four steps (8,4,2,1) give a full 16-lane all-reduce.
template<int CTRL>
__device__ __forceinline__ float dppf(float v) {
    return __int_as_float(__builtin_amdgcn_update_dpp(0, __float_as_int(v), CTRL, 0xF, 0xF, true));
}
template<int CTRL>
__device__ __forceinline__ int dppi(int v) {
    return __builtin_amdgcn_update_dpp(0, v, CTRL, 0xF, 0xF, true);
}

// ---------------- prep: coalesced, 128 blocks ----------------
__global__ __launch_bounds__(256) void prep_kernel(const float* __restrict__ cb,
                                                   float* __restrict__ ws) {
    int gid = blockIdx.x * 256 + threadIdx.x;   // 0..32767
    if (gid < 4) ws[gid] = 0.f;
    if (gid < 8192) ws[WS_AVGP + gid] = 0.f;    // 8x1024 replica region

    int k  = gid >> 5;
    int s  = gid & 31;
    int kc = s >> 2;
    int qq = s & 3;

    if (gid < 1024) {
        // c2 on the EXACT round-1 grid (sequential float4 chain), one thread per row
        const float4* row = (const float4*)(cb + (size_t)gid * DIM);
        float ssum = 0.f;
#pragma unroll 8
        for (int i = 0; i < DIM / 4; ++i) {
            float4 v = row[i];
            ssum += v.x * v.x + v.y * v.y + v.z * v.z + v.w * v.w;
        }
        ws[WS_C2 + gid] = ssum;
    }

    // fragment-ordered hi-bf16: chunk[((kc*1024 + k)*4 + qq)] = bf16(cb[k][kc*32+qq*8 .. +8])
    unsigned short* cbf = (unsigned short*)(ws + WS_CBF);
    const float* src = cb + (size_t)k * DIM + (kc << 5) + (qq << 3);
    float4 v0 = *(const float4*)src, v1 = *(const float4*)(src + 4);
    u16x8 o;
    o[0] = f2bf(v0.x); o[1] = f2bf(v0.y); o[2] = f2bf(v0.z); o[3] = f2bf(v0.w);
    o[4] = f2bf(v1.x); o[5] = f2bf(v1.y); o[6] = f2bf(v1.z); o[7] = f2bf(v1.w);
    *(u16x8*)(cbf + ((((size_t)(kc << 10) + k) << 2) + qq) * 8) = o;
}

// ---------------- main fused kernel ----------------
// TM=64 / 1024 threads (16 waves = 2 row-halves x 8 col-groups).
// x staged TWICE in LDS: fp32 (E4b exact refinement) + bf16 (main loop, converted once).
// This round: E0/E2 16-lane reductions moved from __shfl_xor (ds_bpermute chains) to
// DPP row_ror VALU all-reduces — removes 128 DS ops/thread from the epilogue.
__global__ __launch_bounds__(1024, 4) void vq_main(const float* __restrict__ x,
                                                   const float* __restrict__ cb,
                                                   float* __restrict__ ws,
                                                   float* __restrict__ out) {
    __shared__ float epi[EP_SIZE];
    __shared__ float xs[64 * XPITCH];         // 66560 B fp32 x tile
    __shared__ unsigned short xbf[64 * XBU];  // 33792 B bf16 x tile

    const int tid  = threadIdx.x;
    const int w    = tid >> 6;       // 0..15
    const int lane = tid & 63;
    const int m    = lane & 15;
    const int q    = lane >> 4;
    const int wc   = w & 7;          // column group
    const int rh   = w >> 3;         // row half
    const int R0   = blockIdx.x * TM;

    const u16x8* cbf = (const u16x8*)(ws + WS_CBF);
    // chunk index = (kc*1024 + c)*4 + q, c = h*512 + wc*64 + ct*16 + m
    const u16x8* bbase = cbf + (((wc << 6) + m) << 2) + q;
    // steps in u16x8 units: kc: 4096, h: 2048, ct: 64

    u16x8 breg[2][4];
    bf16x8 ah[2];

    // ---- stage x rows (wave w -> rows 4w..4w+3); longest-latency loads first
    float4 t0 = *((const float4*)(x + (size_t)(R0 + (w << 2) + 0) * DIM) + lane);
    float4 t1 = *((const float4*)(x + (size_t)(R0 + (w << 2) + 1) * DIM) + lane);
    float4 t2 = *((const float4*)(x + (size_t)(R0 + (w << 2) + 2) * DIM) + lane);
    float4 t3 = *((const float4*)(x + (size_t)(R0 + (w << 2) + 3) * DIM) + lane);

    // B prologue loads go out while x loads are in flight
    {
        const u16x8* p = bbase;  // sub 0: kc=0,h=0
        breg[0][0] = p[0]; breg[0][1] = p[64]; breg[0][2] = p[128]; breg[0][3] = p[192];
    }

    // fp32 copy (E4b) + bf16 copy (MFMA loop) — f2bf on the same register values
    *((float4*)(xs + ((w << 2) + 0) * XPITCH) + lane) = t0;
    *((float4*)(xs + ((w << 2) + 1) * XPITCH) + lane) = t1;
    *((float4*)(xs + ((w << 2) + 2) * XPITCH) + lane) = t2;
    *((float4*)(xs + ((w << 2) + 3) * XPITCH) + lane) = t3;
    {
        u16x4 o;
        o[0] = f2bf(t0.x); o[1] = f2bf(t0.y); o[2] = f2bf(t0.z); o[3] = f2bf(t0.w);
        *(u16x4*)(xbf + ((w << 2) + 0) * XBU + (lane << 2)) = o;
        o[0] = f2bf(t1.x); o[1] = f2bf(t1.y); o[2] = f2bf(t1.z); o[3] = f2bf(t1.w);
        *(u16x4*)(xbf + ((w << 2) + 1) * XBU + (lane << 2)) = o;
        o[0] = f2bf(t2.x); o[1] = f2bf(t2.y); o[2] = f2bf(t2.z); o[3] = f2bf(t2.w);
        *(u16x4*)(xbf + ((w << 2) + 2) * XBU + (lane << 2)) = o;
        o[0] = f2bf(t3.x); o[1] = f2bf(t3.y); o[2] = f2bf(t3.z); o[3] = f2bf(t3.w);
        *(u16x4*)(xbf + ((w << 2) + 3) * XBU + (lane << 2)) = o;
    }

    f32x4 acc[2][8];
#pragma unroll
    for (int a = 0; a < 2; ++a)
#pragma unroll
        for (int b = 0; b < 8; ++b) acc[a][b] = (f32x4)0.f;

    __syncthreads();

    const int rbase = rh << 5;       // wave's 32-row base inside the LDS tile
    ah[0] = __builtin_bit_cast(bf16x8, *(const u16x8*)(xbf + (rbase + m) * XBU + (q << 3)));
    ah[1] = __builtin_bit_cast(bf16x8, *(const u16x8*)(xbf + (rbase + 16 + m) * XBU + (q << 3)));

#pragma unroll
    for (int sub = 0; sub < 16; ++sub) {
        const int pb = sub & 1;
        if (sub < 15) {
            const int ns = sub + 1;
            const u16x8* p = bbase + ((ns >> 1) << 12) + ((ns & 1) << 11);
            breg[pb ^ 1][0] = p[0];   breg[pb ^ 1][1] = p[64];
            breg[pb ^ 1][2] = p[128]; breg[pb ^ 1][3] = p[192];
        }
#pragma unroll
        for (int ct = 0; ct < 4; ++ct) {
            bf16x8 bh = __builtin_bit_cast(bf16x8, breg[pb][ct]);
            int cg = ((sub & 1) << 2) + ct;
            acc[0][cg] = __builtin_amdgcn_mfma_f32_16x16x32_bf16(ah[0], bh, acc[0][cg], 0, 0, 0);
            acc[1][cg] = __builtin_amdgcn_mfma_f32_16x16x32_bf16(ah[1], bh, acc[1][cg], 0, 0, 0);
        }
        if ((sub & 1) == 1 && sub < 15) {
            const int nkc = (sub >> 1) + 1;
            ah[0] = __builtin_bit_cast(bf16x8,
                *(const u16x8*)(xbf + (rbase + m) * XBU + (nkc << 5) + (q << 3)));
            ah[1] = __builtin_bit_cast(bf16x8,
                *(const u16x8*)(xbf + (rbase + 16 + m) * XBU + (nkc << 5) + (q << 3)));
        }
    }

    // ================= epilogue (rows = 64) =================
    // E0: zero accumulators; g = c2 - 2*acc (screen grid); per-wave per-row argmin
    if (tid < 64) ((int*)(epi + EP_CNT))[tid] = 0;
    epi[EP_AVGP + tid] = 0.f;            // 1024 threads, one each

    float c2v[8];
#pragma unroll
    for (int cg = 0; cg < 8; ++cg) {
        int col = ((cg >> 2) << 9) + (wc << 6) + ((cg & 3) << 4) + m;
        c2v[cg] = ws[WS_C2 + col];
    }
#pragma unroll
    for (int rt = 0; rt < 2; ++rt) {
#pragma unroll
        for (int reg = 0; reg < 4; ++reg) {
            int row = rbase + (rt << 4) + (q << 2) + reg;
            float md = 3.0e38f; int mk = 0;
#pragma unroll
            for (int cg = 0; cg < 8; ++cg) {
                float g = c2v[cg] - 2.0f * acc[rt][cg][reg];
                acc[rt][cg][reg] = g;
                int col = ((cg >> 2) << 9) + (wc << 6) + ((cg & 3) << 4) + m;
                if (g < md) { md = g; mk = col; }
            }
            // DPP row_ror all-reduce over the 16 m-lanes (lexicographic min: exact)
            {
                float od; int ok;
                od = dppf<0x128>(md); ok = dppi<0x128>(mk);
                if (od < md || (od == md && ok < mk)) { md = od; mk = ok; }
                od = dppf<0x124>(md); ok = dppi<0x124>(mk);
                if (od < md || (od == md && ok < mk)) { md = od; mk = ok; }
                od = dppf<0x122>(md); ok = dppi<0x122>(mk);
                if (od < md || (od == md && ok < mk)) { md = od; mk = ok; }
                od = dppf<0x121>(md); ok = dppi<0x121>(mk);
                if (od < md || (od == md && ok < mk)) { md = od; mk = ok; }
            }
            if (m == 0) {
                epi[EP_REDD + (wc << 6) + row] = md;
                ((int*)(epi + EP_REDK))[(wc << 6) + row] = mk;
            }
        }
    }
    __syncthreads();

    // E1: cross-group min per row
    if (tid < 64) {
        float gm = 3.0e38f;
#pragma unroll
        for (int g = 0; g < 8; ++g) {
            float d = epi[EP_REDD + (g << 6) + tid];
            if (d < gm) gm = d;
        }
        epi[EP_GMIN + tid] = gm;
    }
    __syncthreads();

    // E2: exp pass + candidate collection + per-wave T1/T2 (DPP sums)
    {
        int* cnt  = (int*)(epi + EP_CNT);
        int* cand = (int*)(epi + EP_CAND);
#pragma unroll
        for (int rt = 0; rt < 2; ++rt) {
#pragma unroll
            for (int reg = 0; reg < 4; ++reg) {
                int row = rbase + (rt << 4) + (q << 2) + reg;
                float gm = epi[EP_GMIN + row];
                float t1 = 0.f, t2 = 0.f;
#pragma unroll
                for (int cg = 0; cg < 8; ++cg) {
                    float g = acc[rt][cg][reg];
                    if (g < gm + DELTA) {
                        int col = ((cg >> 2) << 9) + (wc << 6) + ((cg & 3) << 4) + m;
                        int pos = atomicAdd(&cnt[row], 1);
                        if (pos < 16) cand[(row << 4) + pos] = col;
                    }
                    float z = -100.0f * (g - gm);
                    float e = __expf(z);
                    acc[rt][cg][reg] = e;
                    t1 += e;
                    t2 += e * z;
                }
                // DPP row_ror all-reduce sums over the 16 m-lanes
                t1 += dppf<0x128>(t1); t2 += dppf<0x128>(t2);
                t1 += dppf<0x124>(t1); t2 += dppf<0x124>(t2);
                t1 += dppf<0x122>(t1); t2 += dppf<0x122>(t2);
                t1 += dppf<0x121>(t1); t2 += dppf<0x121>(t2);
                if (m == 0) {
                    epi[EP_RT1 + (wc << 6) + row] = t1;
                    epi[EP_RT2 + (wc << 6) + row] = t2;
                }
            }
        }
    }
    __syncthreads();

    // E3: finalize per-row softmax stats
    if (tid < 64) {
        float T1 = 0.f, T2 = 0.f;
#pragma unroll
        for (int g = 0; g < 8; ++g) {
            T1 += epi[EP_RT1 + (g << 6) + tid];
            T2 += epi[EP_RT2 + (g << 6) + tid];
        }
        float r1 = 1.0f / T1;
        epi[EP_R1F + tid] = r1;
        epi[EP_SP + tid]  = T2 * r1 - logf(T1);
    }
    __syncthreads();

    // E4a: avg_probs column sums (row-halves combined with a staggered += across barriers)
    float sv[8];
    {
        float r1v[2][4];
#pragma unroll
        for (int rt = 0; rt < 2; ++rt)
#pragma unroll
            for (int reg = 0; reg < 4; ++reg)
                r1v[rt][reg] = epi[EP_R1F + rbase + (rt << 4) + (q << 2) + reg];
#pragma unroll
        for (int cg = 0; cg < 8; ++cg) {
            float s = 0.f;
#pragma unroll
            for (int rt = 0; rt < 2; ++rt)
#pragma unroll
                for (int reg = 0; reg < 4; ++reg)
                    s += acc[rt][cg][reg] * r1v[rt][reg];
            s += __shfl_xor(s, 16, 64);
            s += __shfl_xor(s, 32, 64);
            sv[cg] = s;
        }
        if (rh == 0 && lane < 16) {
#pragma unroll
            for (int cg = 0; cg < 8; ++cg) {
                int col = ((cg >> 2) << 9) + (wc << 6) + ((cg & 3) << 4) + m;
                epi[EP_AVGP + col] += sv[cg];
            }
        }
    }
    // E4b: candidate refinement on the EXACT round-1/np grid:
    //      d = (x2 - 2*ab) + c2; ab sequential fmaf chain; ax from fp32 LDS; unrolled.
    {
        int* cnt  = (int*)(epi + EP_CNT);
        int* cand = (int*)(epi + EP_CAND);
        int r = tid >> 4;          // 64 rows x 16 threads = 1024
        int i = tid & 15;
        int n = cnt[r]; if (n > 16) n = 16;
        if (i < n) {
            int k = cand[(r << 4) + i];
            const float4* ax = (const float4*)(xs + r * XPITCH);
            const float4* bx = (const float4*)(cb + (((size_t)k) << 8));
            float ab = 0.f, x2 = 0.f;
#pragma unroll 8
            for (int d4 = 0; d4 < 64; ++d4) {
                float4 a = ax[d4], b = bx[d4];
                ab = fmaf(a.x, b.x, ab);
                ab = fmaf(a.y, b.y, ab);
                ab = fmaf(a.z, b.z, ab);
                ab = fmaf(a.w, b.w, ab);
                x2 += a.x * a.x + a.y * a.y + a.z * a.z + a.w * a.w;
            }
            float t = 2.0f * ab;
            epi[EP_CEX + (r << 4) + i] = (x2 - t) + ws[WS_C2 + k];
        }
    }
    __syncthreads();

    // second half of E4a (race-free via the barrier above)
    if (rh == 1 && lane < 16) {
#pragma unroll
        for (int cg = 0; cg < 8; ++cg) {
            int col = ((cg >> 2) << 9) + (wc << 6) + ((cg & 3) << 4) + m;
            epi[EP_AVGP + col] += sv[cg];
        }
    }

    // E5: final per-row selection (min d, lowest-index tie-break) + index output
    if (tid < 64) {
        int* cnt  = (int*)(epi + EP_CNT);
        int* cand = (int*)(epi + EP_CAND);
        int n = cnt[tid]; if (n > 16) n = 16;
        float bd = epi[EP_CEX + (tid << 4)];
        int   bk = cand[(tid << 4)];
        for (int i = 1; i < n; ++i) {
            float d = epi[EP_CEX + (tid << 4) + i];
            int   k = cand[(tid << 4) + i];
            if (d < bd || (d == bd && k < bk)) { bd = d; bk = k; }
        }
        ((int*)(epi + EP_KFIN))[tid] = bk;
        epi[EP_DFIN + tid] = bd;
        out[IDXOFF + R0 + tid] = (float)bk;
    }
    __syncthreads();

    // E6: quantized gather (wave w -> rows w*4..w*4+3, nt stores), global accumulators
#pragma unroll
    for (int rr = 0; rr < 4; ++rr) {
        int r = (w << 2) + rr;
        int k = ((int*)(epi + EP_KFIN))[r];
        f32x4 v = *((const f32x4*)(cb + (((size_t)k) << 8)) + lane);
        __builtin_nontemporal_store(v, (f32x4*)(out + (((size_t)(R0 + r)) << 8)) + lane);
    }
    // replicated avg_probs accumulator: contention /8
    atomicAdd(ws + WS_AVGP + ((blockIdx.x & 7) << 10) + tid, epi[EP_AVGP + tid]);
    if (tid < 64) {
        float sp = epi[EP_SP + tid];
        float dd = epi[EP_DFIN + tid];
#pragma unroll
        for (int off = 1; off <= 32; off <<= 1) {
            sp += __shfl_xor(sp, off, 64);
            dd += __shfl_xor(dd, off, 64);
        }
        if (tid == 0) {
            atomicAdd(ws + WS_PLP, sp);
            atomicAdd(ws + WS_DMIN, dd);
        }
    }
}

// ---------------- finalize ----------------
__global__ __launch_bounds__(256) void vq_finalize(const float* __restrict__ ws,
                                                   float* __restrict__ out) {
    __shared__ float red[4];
    int tid = threadIdx.x;
    float part = 0.f;
    for (int k = tid; k < 1024; k += 256) {
        float s = 0.f;
#pragma unroll
        for (int r = 0; r < 8; ++r) s += ws[WS_AVGP + (r << 10) + k];
        float ap = s * (1.0f / 65536.0f);
        part += ap * logf(ap + 1e-5f);
    }
#pragma unroll
    for (int off = 32; off; off >>= 1) part += __shfl_xor(part, off, 64);
    if ((tid & 63) == 0) red[tid >> 6] = part;
    __syncthreads();
    if (tid == 0) {
        float sum_aplog      = red[0] + red[1] + red[2] + red[3];
        float avg_entropy    = -sum_aplog;
        float sample_entropy = -ws[WS_PLP] * (1.0f / 65536.0f);
        float entropy_loss   = (sample_entropy - avg_entropy) * 0.1f;
        float eq = 1.25f * ws[WS_DMIN] * (1.0f / ((float)NROWS * (float)DIM));
        out[QOFF] = eq + entropy_loss;
    }
}

extern "C" void kernel_launch(void* const* d_in, const int* in_sizes, int n_in,
                              void* d_out, int out_size, void* d_ws, size_t ws_size,
                              hipStream_t stream) {
    const float* x  = (const float*)d_in[0];
    const float* cb = (const float*)d_in[1];
    float* out = (float*)d_out;
    float* ws  = (float*)d_ws;

    prep_kernel<<<128, 256, 0, stream>>>(cb, ws);
    vq_main<<<NBLK, 1024, 0, stream>>>(x, cb, ws, out);
    vq_finalize<<<1, 256, 0, stream>>>(ws, out);
}

// Round 7
// 248.759 us; speedup vs baseline: 1.1139x; 1.0446x over previous
//
#include <hip/hip_runtime.h>
#include <math.h>

#define NROWS 65536
#define DIM   256
#define KCB   1024
#define TM    64
#define NBLK  (NROWS / TM)     // 1024
#define QOFF  (NROWS * DIM)
#define IDXOFF (QOFF + 1)

// ws float layout
#define WS_DMIN 0
#define WS_PLP  1
#define WS_AVGP 4                        // 8 replicas x 1024 floats (atomic contention /8)
#define WS_C2   (WS_AVGP + 8 * 1024)
#define WS_CBF  (WS_C2 + 1024)           // fragment-ordered hi-bf16 codebook, 131072 ushort

#define DELTA 0.05f
#define XPITCH 260                       // fp32 LDS x pitch (floats)

typedef __attribute__((ext_vector_type(8))) __bf16 bf16x8;
typedef __attribute__((ext_vector_type(4))) float  f32x4;
typedef __attribute__((ext_vector_type(8))) unsigned short u16x8;

// epilogue LDS float offsets (static shared, 5504 floats = 22016 B)
#define EP_REDD 0       // [8][64]
#define EP_REDK 512     // [8][64] int
#define EP_RT1  1024    // [8][64]
#define EP_RT2  1536    // [8][64]
#define EP_GMIN 2048    // 64
#define EP_CNT  2112    // 64 int
#define EP_CAND 2176    // 64*16 int
#define EP_CEX  3200    // 64*16
#define EP_R1F  4224    // 64
#define EP_SP   4288    // 64
#define EP_KFIN 4352    // 64 int
#define EP_DFIN 4416    // 64
#define EP_AVGP 4480    // 1024
#define EP_SIZE 5504

__device__ __forceinline__ unsigned short f2bf(float f) {
    unsigned u = __float_as_uint(f);
    u += 0x7fffu + ((u >> 16) & 1u);
    return (unsigned short)(u >> 16);
}

__device__ __forceinline__ bf16x8 cvt8(const float* src) {
    float4 v0 = *(const float4*)src, v1 = *(const float4*)(src + 4);
    u16x8 o;
    o[0] = f2bf(v0.x); o[1] = f2bf(v0.y); o[2] = f2bf(v0.z); o[3] = f2bf(v0.w);
    o[4] = f2bf(v1.x); o[5] = f2bf(v1.y); o[6] = f2bf(v1.z); o[7] = f2bf(v1.w);
    return __builtin_bit_cast(bf16x8, o);
}

// async global->LDS DMA, 16 B per lane; lds dest = wave-uniform base + lane*16
__device__ __forceinline__ void gload_lds16(const void* g, void* l) {
    __builtin_amdgcn_global_load_lds(
        (const __attribute__((address_space(1))) unsigned int*)g,
        (__attribute__((address_space(3))) unsigned int*)l, 16, 0, 0);
}

// ---------------- prep: coalesced, 128 blocks ----------------
__global__ __launch_bounds__(256) void prep_kernel(const float* __restrict__ cb,
                                                   float* __restrict__ ws) {
    int gid = blockIdx.x * 256 + threadIdx.x;   // 0..32767
    if (gid < 4) ws[gid] = 0.f;
    if (gid < 8192) ws[WS_AVGP + gid] = 0.f;    // 8x1024 replica region

    int k  = gid >> 5;
    int s  = gid & 31;
    int kc = s >> 2;
    int qq = s & 3;

    if (gid < 1024) {
        // c2 on the EXACT round-1 grid (sequential float4 chain), one thread per row
        const float4* row = (const float4*)(cb + (size_t)gid * DIM);
        float ssum = 0.f;
#pragma unroll 8
        for (int i = 0; i < DIM / 4; ++i) {
            float4 v = row[i];
            ssum += v.x * v.x + v.y * v.y + v.z * v.z + v.w * v.w;
        }
        ws[WS_C2 + gid] = ssum;
    }

    // fragment-ordered hi-bf16: chunk[((kc*1024 + k)*4 + qq)] = bf16(cb[k][kc*32+qq*8 .. +8])
    unsigned short* cbf = (unsigned short*)(ws + WS_CBF);
    const float* src = cb + (size_t)k * DIM + (kc << 5) + (qq << 3);
    float4 v0 = *(const float4*)src, v1 = *(const float4*)(src + 4);
    u16x8 o;
    o[0] = f2bf(v0.x); o[1] = f2bf(v0.y); o[2] = f2bf(v0.z); o[3] = f2bf(v0.w);
    o[4] = f2bf(v1.x); o[5] = f2bf(v1.y); o[6] = f2bf(v1.z); o[7] = f2bf(v1.w);
    *(u16x8*)(cbf + ((((size_t)(kc << 10) + k) << 2) + qq) * 8) = o;
}

// ---------------- main fused kernel ----------------
// TM=64 / 1024 threads (16 waves = 2 row-halves x 8 col-groups).
// B staged through LDS via global_load_lds (32 KB/sub, double-buffered): one copy per
// block instead of per-row-half -> codebook L2 traffic halves (1 GB -> 0.53 GB) and the
// per-wave flat-load latency chain is replaced by DMA + barrier pipelining.
// x staged once in LDS as fp32; A-fragments use in-loop cvt8 (R3 path, bit-identical).
__global__ __launch_bounds__(1024, 4) void vq_main(const float* __restrict__ x,
                                                   const float* __restrict__ cb,
                                                   float* __restrict__ ws,
                                                   float* __restrict__ out) {
    __shared__ float epi[EP_SIZE];
    __shared__ float xs[64 * XPITCH];       // 66560 B fp32 x tile
    __shared__ u16x8 ldsB[2][2048];         // 65536 B B double buffer (32 KB each)

    const int tid  = threadIdx.x;
    const int w    = tid >> 6;       // 0..15
    const int lane = tid & 63;
    const int m    = lane & 15;
    const int q    = lane >> 4;
    const int wc   = w & 7;          // column group
    const int rh   = w >> 3;         // row half
    const int R0   = blockIdx.x * TM;

    const char* gB = (const char*)(ws + WS_CBF);   // fragment-ordered codebook base
    // within a sub's 2048-chunk region: frag chunk = (wc*64 + ct*16 + m)*4 + q, ct step 64
    const int fragoff = (wc << 8) + (m << 2) + q;

    bf16x8 ah[2];

    // ---- stage x rows (wave w -> rows 4w..4w+3); HBM loads issued first
    float4 t0 = *((const float4*)(x + (size_t)(R0 + (w << 2) + 0) * DIM) + lane);
    float4 t1 = *((const float4*)(x + (size_t)(R0 + (w << 2) + 1) * DIM) + lane);
    float4 t2 = *((const float4*)(x + (size_t)(R0 + (w << 2) + 2) * DIM) + lane);
    float4 t3 = *((const float4*)(x + (size_t)(R0 + (w << 2) + 3) * DIM) + lane);

    // stage sub 0 into buf0 (async DMA, overlaps the x loads)
    {
        const char* g = gB + (size_t)tid * 16;
        char* l = (char*)&ldsB[0][0] + (w << 10);
        gload_lds16(g, l);
        gload_lds16(g + 16384, l + 16384);
    }

    *((float4*)(xs + ((w << 2) + 0) * XPITCH) + lane) = t0;
    *((float4*)(xs + ((w << 2) + 1) * XPITCH) + lane) = t1;
    *((float4*)(xs + ((w << 2) + 2) * XPITCH) + lane) = t2;
    *((float4*)(xs + ((w << 2) + 3) * XPITCH) + lane) = t3;

    f32x4 acc[2][8];
#pragma unroll
    for (int a = 0; a < 2; ++a)
#pragma unroll
        for (int b = 0; b < 8; ++b) acc[a][b] = (f32x4)0.f;

    __syncthreads();   // drains staging DMA (vmcnt) + xs writes (lgkm)

    const int rbase = rh << 5;       // wave's 32-row base inside the LDS tile
    ah[0] = cvt8(xs + (rbase + m) * XPITCH + (q << 3));
    ah[1] = cvt8(xs + (rbase + 16 + m) * XPITCH + (q << 3));

#pragma unroll
    for (int sub = 0; sub < 16; ++sub) {
        const int cur = sub & 1;
        if (sub < 15) {
            // async-stage sub+1 into the other buffer (its last readers finished
            // before the barrier that ended the previous iteration)
            const char* g = gB + (size_t)(sub + 1) * 32768 + (size_t)tid * 16;
            char* l = (char*)&ldsB[cur ^ 1][0] + (w << 10);
            gload_lds16(g, l);
            gload_lds16(g + 16384, l + 16384);
        }
        const u16x8* lbc = &ldsB[cur][fragoff];
        u16x8 f0 = lbc[0], f1 = lbc[64], f2 = lbc[128], f3 = lbc[192];
#pragma unroll
        for (int ct = 0; ct < 4; ++ct) {
            u16x8 fr = (ct == 0) ? f0 : (ct == 1) ? f1 : (ct == 2) ? f2 : f3;
            bf16x8 bh = __builtin_bit_cast(bf16x8, fr);
            int cg = ((sub & 1) << 2) + ct;
            acc[0][cg] = __builtin_amdgcn_mfma_f32_16x16x32_bf16(ah[0], bh, acc[0][cg], 0, 0, 0);
            acc[1][cg] = __builtin_amdgcn_mfma_f32_16x16x32_bf16(ah[1], bh, acc[1][cg], 0, 0, 0);
        }
        if ((sub & 1) == 1 && sub < 15) {
            const int nkc = (sub >> 1) + 1;
            ah[0] = cvt8(xs + (rbase + m) * XPITCH + (nkc << 5) + (q << 3));
            ah[1] = cvt8(xs + (rbase + 16 + m) * XPITCH + (nkc << 5) + (q << 3));
        }
        if (sub < 15) __syncthreads();   // staging of sub+1 complete & visible
    }

    // ================= epilogue (rows = 64) =================
    // E0: zero accumulators; g = c2 - 2*acc (screen grid); per-wave per-row argmin
    if (tid < 64) ((int*)(epi + EP_CNT))[tid] = 0;
    epi[EP_AVGP + tid] = 0.f;            // 1024 threads, one each

    float c2v[8];
#pragma unroll
    for (int cg = 0; cg < 8; ++cg) {
        int col = ((cg >> 2) << 9) + (wc << 6) + ((cg & 3) << 4) + m;
        c2v[cg] = ws[WS_C2 + col];
    }
#pragma unroll
    for (int rt = 0; rt < 2; ++rt) {
#pragma unroll
        for (int reg = 0; reg < 4; ++reg) {
            int row = rbase + (rt << 4) + (q << 2) + reg;
            float md = 3.0e38f; int mk = 0;
#pragma unroll
            for (int cg = 0; cg < 8; ++cg) {
                float g = c2v[cg] - 2.0f * acc[rt][cg][reg];
                acc[rt][cg][reg] = g;
                int col = ((cg >> 2) << 9) + (wc << 6) + ((cg & 3) << 4) + m;
                if (g < md) { md = g; mk = col; }
            }
#pragma unroll
            for (int off = 1; off <= 8; off <<= 1) {
                float od = __shfl_xor(md, off, 64);
                int   ok = __shfl_xor(mk, off, 64);
                if (od < md || (od == md && ok < mk)) { md = od; mk = ok; }
            }
            if (m == 0) {
                epi[EP_REDD + (wc << 6) + row] = md;
                ((int*)(epi + EP_REDK))[(wc << 6) + row] = mk;
            }
        }
    }
    __syncthreads();

    // E1: cross-group min per row
    if (tid < 64) {
        float gm = 3.0e38f;
#pragma unroll
        for (int g = 0; g < 8; ++g) {
            float d = epi[EP_REDD + (g << 6) + tid];
            if (d < gm) gm = d;
        }
        epi[EP_GMIN + tid] = gm;
    }
    __syncthreads();

    // E2: exp pass + candidate collection + per-wave T1/T2
    {
        int* cnt  = (int*)(epi + EP_CNT);
        int* cand = (int*)(epi + EP_CAND);
#pragma unroll
        for (int rt = 0; rt < 2; ++rt) {
#pragma unroll
            for (int reg = 0; reg < 4; ++reg) {
                int row = rbase + (rt << 4) + (q << 2) + reg;
                float gm = epi[EP_GMIN + row];
                float t1 = 0.f, t2 = 0.f;
#pragma unroll
                for (int cg = 0; cg < 8; ++cg) {
                    float g = acc[rt][cg][reg];
                    if (g < gm + DELTA) {
                        int col = ((cg >> 2) << 9) + (wc << 6) + ((cg & 3) << 4) + m;
                        int pos = atomicAdd(&cnt[row], 1);
                        if (pos < 16) cand[(row << 4) + pos] = col;
                    }
                    float z = -100.0f * (g - gm);
                    float e = __expf(z);
                    acc[rt][cg][reg] = e;
                    t1 += e;
                    t2 += e * z;
                }
#pragma unroll
                for (int off = 1; off <= 8; off <<= 1) {
                    t1 += __shfl_xor(t1, off, 64);
                    t2 += __shfl_xor(t2, off, 64);
                }
                if (m == 0) {
                    epi[EP_RT1 + (wc << 6) + row] = t1;
                    epi[EP_RT2 + (wc << 6) + row] = t2;
                }
            }
        }
    }
    __syncthreads();

    // E3: finalize per-row softmax stats
    if (tid < 64) {
        float T1 = 0.f, T2 = 0.f;
#pragma unroll
        for (int g = 0; g < 8; ++g) {
            T1 += epi[EP_RT1 + (g << 6) + tid];
            T2 += epi[EP_RT2 + (g << 6) + tid];
        }
        float r1 = 1.0f / T1;
        epi[EP_R1F + tid] = r1;
        epi[EP_SP + tid]  = T2 * r1 - logf(T1);
    }
    __syncthreads();

    // E4a: avg_probs column sums (row-halves combined with a staggered += across barriers)
    float sv[8];
    {
        float r1v[2][4];
#pragma unroll
        for (int rt = 0; rt < 2; ++rt)
#pragma unroll
            for (int reg = 0; reg < 4; ++reg)
                r1v[rt][reg] = epi[EP_R1F + rbase + (rt << 4) + (q << 2) + reg];
#pragma unroll
        for (int cg = 0; cg < 8; ++cg) {
            float s = 0.f;
#pragma unroll
            for (int rt = 0; rt < 2; ++rt)
#pragma unroll
                for (int reg = 0; reg < 4; ++reg)
                    s += acc[rt][cg][reg] * r1v[rt][reg];
            s += __shfl_xor(s, 16, 64);
            s += __shfl_xor(s, 32, 64);
            sv[cg] = s;
        }
        if (rh == 0 && lane < 16) {
#pragma unroll
            for (int cg = 0; cg < 8; ++cg) {
                int col = ((cg >> 2) << 9) + (wc << 6) + ((cg & 3) << 4) + m;
                epi[EP_AVGP + col] += sv[cg];
            }
        }
    }
    // E4b: candidate refinement on the EXACT round-1/np grid:
    //      d = (x2 - 2*ab) + c2; ab sequential fmaf chain; ax from fp32 LDS; unrolled.
    {
        int* cnt  = (int*)(epi + EP_CNT);
        int* cand = (int*)(epi + EP_CAND);
        int r = tid >> 4;          // 64 rows x 16 threads = 1024
        int i = tid & 15;
        int n = cnt[r]; if (n > 16) n = 16;
        if (i < n) {
            int k = cand[(r << 4) + i];
            const float4* ax = (const float4*)(xs + r * XPITCH);
            const float4* bx = (const float4*)(cb + (((size_t)k) << 8));
            float ab = 0.f, x2 = 0.f;
#pragma unroll 8
            for (int d4 = 0; d4 < 64; ++d4) {
                float4 a = ax[d4], b = bx[d4];
                ab = fmaf(a.x, b.x, ab);
                ab = fmaf(a.y, b.y, ab);
                ab = fmaf(a.z, b.z, ab);
                ab = fmaf(a.w, b.w, ab);
                x2 += a.x * a.x + a.y * a.y + a.z * a.z + a.w * a.w;
            }
            float t = 2.0f * ab;
            epi[EP_CEX + (r << 4) + i] = (x2 - t) + ws[WS_C2 + k];
        }
    }
    __syncthreads();

    // second half of E4a (race-free via the barrier above)
    if (rh == 1 && lane < 16) {
#pragma unroll
        for (int cg = 0; cg < 8; ++cg) {
            int col = ((cg >> 2) << 9) + (wc << 6) + ((cg & 3) << 4) + m;
            epi[EP_AVGP + col] += sv[cg];
        }
    }

    // E5: final per-row selection (min d, lowest-index tie-break) + index output
    if (tid < 64) {
        int* cnt  = (int*)(epi + EP_CNT);
        int* cand = (int*)(epi + EP_CAND);
        int n = cnt[tid]; if (n > 16) n = 16;
        float bd = epi[EP_CEX + (tid << 4)];
        int   bk = cand[(tid << 4)];
        for (int i = 1; i < n; ++i) {
            float d = epi[EP_CEX + (tid << 4) + i];
            int   k = cand[(tid << 4) + i];
            if (d < bd || (d == bd && k < bk)) { bd = d; bk = k; }
        }
        ((int*)(epi + EP_KFIN))[tid] = bk;
        epi[EP_DFIN + tid] = bd;
        out[IDXOFF + R0 + tid] = (float)bk;
    }
    __syncthreads();

    // E6: quantized gather (wave w -> rows w*4..w*4+3, nt stores), global accumulators
#pragma unroll
    for (int rr = 0; rr < 4; ++rr) {
        int r = (w << 2) + rr;
        int k = ((int*)(epi + EP_KFIN))[r];
        f32x4 v = *((const f32x4*)(cb + (((size_t)k) << 8)) + lane);
        __builtin_nontemporal_store(v, (f32x4*)(out + (((size_t)(R0 + r)) << 8)) + lane);
    }
    // replicated avg_probs accumulator: contention /8
    atomicAdd(ws + WS_AVGP + ((blockIdx.x & 7) << 10) + tid, epi[EP_AVGP + tid]);
    if (tid < 64) {
        float sp = epi[EP_SP + tid];
        float dd = epi[EP_DFIN + tid];
#pragma unroll
        for (int off = 1; off <= 32; off <<= 1) {
            sp += __shfl_xor(sp, off, 64);
            dd += __shfl_xor(dd, off, 64);
        }
        if (tid == 0) {
            atomicAdd(ws + WS_PLP, sp);
            atomicAdd(ws + WS_DMIN, dd);
        }
    }
}

// ---------------- finalize ----------------
__global__ __launch_bounds__(256) void vq_finalize(const float* __restrict__ ws,
                                                   float* __restrict__ out) {
    __shared__ float red[4];
    int tid = threadIdx.x;
    float part = 0.f;
    for (int k = tid; k < 1024; k += 256) {
        float s = 0.f;
#pragma unroll
        for (int r = 0; r < 8; ++r) s += ws[WS_AVGP + (r << 10) + k];
        float ap = s * (1.0f / 65536.0f);
        part += ap * logf(ap + 1e-5f);
    }
#pragma unroll
    for (int off = 32; off; off >>= 1) part += __shfl_xor(part, off, 64);
    if ((tid & 63) == 0) red[tid >> 6] = part;
    __syncthreads();
    if (tid == 0) {
        float sum_aplog      = red[0] + red[1] + red[2] + red[3];
        float avg_entropy    = -sum_aplog;
        float sample_entropy = -ws[WS_PLP] * (1.0f / 65536.0f);
        float entropy_loss   = (sample_entropy - avg_entropy) * 0.1f;
        float eq = 1.25f * ws[WS_DMIN] * (1.0f / ((float)NROWS * (float)DIM));
        out[QOFF] = eq + entropy_loss;
    }
}

extern "C" void kernel_launch(void* const* d_in, const int* in_sizes, int n_in,
                              void* d_out, int out_size, void* d_ws, size_t ws_size,
                              hipStream_t stream) {
    const float* x  = (const float*)d_in[0];
    const float* cb = (const float*)d_in[1];
    float* out = (float*)d_out;
    float* ws  = (float*)d_ws;

    prep_kernel<<<128, 256, 0, stream>>>(cb, ws);
    vq_main<<<NBLK, 1024, 0, stream>>>(x, cb, ws, out);
    vq_finalize<<<1, 256, 0, stream>>>(ws, out);
}